// Round 1
// baseline (307.048 us; speedup 1.0000x reference)
//
#include <hip/hip_runtime.h>
#include <stdint.h>

#pragma clang fp contract(off)

#define NUM_CLASSES 81
#define TOP_K 200
#define BATCH 32
#define NUM_PRIORS 16384
#define CAP 512
#define CONF_T 0.01f
#define NMS_T 0.45f

typedef unsigned long long u64;
typedef unsigned int u32;

// Correctly-rounded f32 exp via f64 — round-0 guess for matching the host
// reference's expf. If absmax shows keep-flips, swap for a cephes replica.
__device__ __forceinline__ float exp_ref(float x) {
#pragma clang fp contract(off)
    return (float)exp((double)x);
}

struct SharedBlk {
    u64 keys[CAP];          // gathered candidate keys (bits(score)<<32 | ~p)
    u64 sup[TOP_K][4];      // suppression bitmask rows (bits k>j with iou>thr)
    float box[TOP_K][4];    // x1,y1,x2,y2
    float area[TOP_K];
    float score[TOP_K];
    u64 keep[4];
    u32 acc;                // count accumulator
    u32 ctr;                // gather append counter
};

// Count elements with key > pivot (valid = score > CONF_T; invalid key == 0).
__device__ int count_pass(const float* cbase, u64 pivot, int tid, int lane, u32* s_acc) {
#pragma clang fp contract(off)
    __syncthreads();
    if (tid == 0) *s_acc = 0u;
    __syncthreads();
    u32 ph = (u32)(pivot >> 32), pl = (u32)pivot;
    u32 c = 0;
    for (int j = 0; j < 64; ++j) {
        int p = tid + (j << 8);
        float s = cbase[(size_t)p * NUM_CLASSES];
        bool valid = s > CONF_T;
        u32 bt = valid ? __float_as_uint(s) : 0u;
        u32 il = ~(u32)p;
        c += (valid && ((bt > ph) || ((bt == ph) && (il > pl)))) ? 1u : 0u;
    }
    for (int off = 32; off > 0; off >>= 1) c += __shfl_down(c, off, 64);
    if (lane == 0) atomicAdd(s_acc, c);
    __syncthreads();
    return (int)*s_acc;
}

// Count AND gather (capped at CAP) elements with key > pivot into s_keys.
__device__ int gather_pass(const float* cbase, u64 pivot, int tid, int lane,
                           u64* s_keys, u32* s_acc, u32* s_ctr) {
#pragma clang fp contract(off)
    __syncthreads();
    if (tid == 0) { *s_acc = 0u; *s_ctr = 0u; }
    for (int q = tid; q < CAP; q += 256) s_keys[q] = 0ull;
    __syncthreads();
    u32 ph = (u32)(pivot >> 32), pl = (u32)pivot;
    u32 cnt = 0;
    for (int j = 0; j < 64; ++j) {
        int p = tid + (j << 8);
        float s = cbase[(size_t)p * NUM_CLASSES];
        bool valid = s > CONF_T;
        u32 bt = valid ? __float_as_uint(s) : 0u;
        u32 il = ~(u32)p;
        bool pred = valid && ((bt > ph) || ((bt == ph) && (il > pl)));
        cnt += pred ? 1u : 0u;
        u64 mk = __ballot(pred);
        u32 off = 0;
        if (lane == 0 && mk) off = atomicAdd(s_ctr, (u32)__popcll(mk));
        off = __shfl(off, 0, 64);
        if (pred) {
            u32 pos = off + (u32)__popcll(mk & ((1ull << lane) - 1ull));
            if (pos < CAP) s_keys[pos] = ((u64)bt << 32) | il;
        }
    }
    for (int off2 = 32; off2 > 0; off2 >>= 1) cnt += __shfl_down(cnt, off2, 64);
    if (lane == 0) atomicAdd(s_acc, cnt);
    __syncthreads();
    return (int)*s_acc;
}

__global__ __launch_bounds__(256) void detect_kernel(
    const float* __restrict__ loc_data,   // [B,P,4]
    const float* __restrict__ conf_data,  // [B*P,C]
    const float* __restrict__ prior_data, // [P,4]
    float* __restrict__ out)              // [B,C,K,5], pre-zeroed
{
#pragma clang fp contract(off)
    __shared__ SharedBlk sh;
    const int tid = threadIdx.x;
    const int lane = tid & 63;
    const int wv = tid >> 6;
    const int b = blockIdx.x;
    const int img = b / 80;
    const int r = b - img * 80;
    // XCD-friendly: consecutive blocks (round-robin XCDs) get distant classes;
    // each XCD sees a contiguous 10-class band (cache-line sharing within XCD).
    const int cl = 1 + (r & 7) * 10 + (r >> 3);

    const float* cbase = conf_data + (size_t)img * NUM_PRIORS * NUM_CLASSES + cl;

    // ---- Phase 1: top-CAP candidate gather (speculative pivot + exact fallback)
    u64 pivot = ((u64)__float_as_uint(0.97827148f) << 32) | 0xFFFFFFFFull;
    int m = gather_pass(cbase, pivot, tid, lane, sh.keys, &sh.acc, &sh.ctr);
    if (m < TOP_K || m > CAP) {
        const u32 B001 = __float_as_uint(CONF_T);
        int nvalid = count_pass(cbase, ((u64)B001 << 32) | 0xFFFFFFFFull, tid, lane, &sh.acc);
        if (nvalid <= CAP) {
            pivot = 0ull;  // gather all valid
        } else {
            // exact 64-bit-key binary search: keys distinct => window reachable
            u64 lo = ((u64)B001 << 32) | 0xFFFFFFFFull;  // count(>lo) = nvalid > CAP
            u64 hi = ~0ull;                              // count(>hi) = 0
            for (int it = 0; it < 64; ++it) {
                u64 mid = lo + ((hi - lo) >> 1);
                int c = count_pass(cbase, mid, tid, lane, &sh.acc);
                if (c >= TOP_K && c <= CAP) { pivot = mid; break; }
                if (c > CAP) lo = mid; else hi = mid;
            }
        }
        m = gather_pass(cbase, pivot, tid, lane, sh.keys, &sh.acc, &sh.ctr);
    }
    const int nk = m < TOP_K ? m : TOP_K;

    // ---- Phase 2: bitonic sort CAP keys descending (distinct keys => deterministic)
    for (int k2 = 2; k2 <= CAP; k2 <<= 1) {
        for (int jj = k2 >> 1; jj > 0; jj >>= 1) {
            __syncthreads();
            for (int i = tid; i < CAP; i += 256) {
                int ixj = i ^ jj;
                if (ixj > i) {
                    u64 a = sh.keys[i], bb = sh.keys[ixj];
                    bool up = ((i & k2) == 0);
                    if (up ? (a < bb) : (a > bb)) { sh.keys[i] = bb; sh.keys[ixj] = a; }
                }
            }
        }
    }
    __syncthreads();

    // ---- Phase 3: decode candidate boxes (replicates reference op order exactly)
    for (int q = tid; q < TOP_K * 4; q += 256) ((u64*)sh.sup)[q] = 0ull;
    if (tid < nk) {
        u64 key = sh.keys[tid];
        int p = (int)(~(u32)key);
        float sc = __uint_as_float((u32)(key >> 32));
        const float4 lc = *(const float4*)(loc_data + ((size_t)img * NUM_PRIORS + p) * 4);
        const float4 pr = *(const float4*)(prior_data + (size_t)p * 4);
        float cx = pr.x + (lc.x * 0.1f) * pr.z;
        float cy = pr.y + (lc.y * 0.1f) * pr.w;
        float w  = pr.z * exp_ref(lc.z * 0.2f);
        float h  = pr.w * exp_ref(lc.w * 0.2f);
        float x1 = cx - 0.5f * w;
        float y1 = cy - 0.5f * h;
        float x2 = x1 + w;
        float y2 = y1 + h;
        sh.box[tid][0] = x1; sh.box[tid][1] = y1; sh.box[tid][2] = x2; sh.box[tid][3] = y2;
        sh.area[tid] = fmaxf(x2 - x1, 0.0f) * fmaxf(y2 - y1, 0.0f);
        sh.score[tid] = sc;
    }
    __syncthreads();

    // ---- Phase 4: pairwise suppression bits (j < k, iou > NMS_T)
    for (int idx = tid; idx < TOP_K * TOP_K; idx += 256) {
        int j = idx / TOP_K;
        int k = idx - j * TOP_K;
        if (j < nk && k > j && k < nk) {
            float ltx = fmaxf(sh.box[j][0], sh.box[k][0]);
            float lty = fmaxf(sh.box[j][1], sh.box[k][1]);
            float rbx = fminf(sh.box[j][2], sh.box[k][2]);
            float rby = fminf(sh.box[j][3], sh.box[k][3]);
            float wx = fmaxf(rbx - ltx, 0.0f);
            float wy = fmaxf(rby - lty, 0.0f);
            float inter = wx * wy;
            float uni = (sh.area[j] + sh.area[k]) - inter;
            float iou = inter / fmaxf(uni, 1e-12f);
            if (iou > NMS_T) atomicOr(&sh.sup[j][k >> 6], 1ull << (k & 63));
        }
    }
    __syncthreads();

    // ---- Phase 5: greedy resolve on wave 0 (64-bit chunks, shfl broadcast)
    if (wv == 0) {
        u64 kws[4];
        #pragma unroll
        for (int w = 0; w < 4; ++w) {
            int rem = nk - (w << 6);
            kws[w] = rem >= 64 ? ~0ull : (rem <= 0 ? 0ull : ((1ull << rem) - 1ull));
        }
        for (int c = 0; c < 4; ++c) {
            int row = (c << 6) + lane;
            u64 myrow = (row < TOP_K) ? sh.sup[row][c] : 0ull;
            u64 kw = kws[c];
            u64 nz = __ballot(myrow != 0ull);
            u64 t = kw & nz;
            while (t) {
                int j = __ffsll(t) - 1;
                u64 rj = __shfl(myrow, j, 64);
                kw &= ~rj;         // row j only has bits k > j
                t &= ~(1ull << j);
                t &= kw;           // drop rows j just suppressed
            }
            kws[c] = kw;
            for (int w2 = c + 1; w2 < 4; ++w2) {
                u64 contrib = (row < TOP_K && ((kw >> lane) & 1ull)) ? sh.sup[row][w2] : 0ull;
                #pragma unroll
                for (int off = 32; off > 0; off >>= 1) contrib |= __shfl_xor(contrib, off, 64);
                kws[w2] &= ~contrib;
            }
        }
        if (lane == 0) {
            sh.keep[0] = kws[0]; sh.keep[1] = kws[1];
            sh.keep[2] = kws[2]; sh.keep[3] = kws[3];
        }
    }
    __syncthreads();

    // ---- Phase 6: stable compaction of kept rows
    if (tid < nk) {
        int w = tid >> 6, rr = tid & 63;
        u64 kwv = sh.keep[w];
        if ((kwv >> rr) & 1ull) {
            int pos = __popcll(kwv & ((1ull << rr) - 1ull));
            for (int q = 0; q < w; ++q) pos += __popcll(sh.keep[q]);
            float* o = out + (((size_t)img * NUM_CLASSES + cl) * TOP_K + pos) * 5;
            o[0] = sh.score[tid];
            o[1] = sh.box[tid][0];
            o[2] = sh.box[tid][1];
            o[3] = sh.box[tid][2];
            o[4] = sh.box[tid][3];
        }
    }
}

extern "C" void kernel_launch(void* const* d_in, const int* in_sizes, int n_in,
                              void* d_out, int out_size, void* d_ws, size_t ws_size,
                              hipStream_t stream) {
    const float* loc   = (const float*)d_in[0];
    const float* conf  = (const float*)d_in[1];
    const float* prior = (const float*)d_in[2];
    float* out = (float*)d_out;

    hipMemsetAsync(d_out, 0, (size_t)out_size * sizeof(float), stream);

    dim3 grid(BATCH * (NUM_CLASSES - 1));  // 2560 tasks: one block per (image, class)
    detect_kernel<<<grid, 256, 0, stream>>>(loc, conf, prior, out);
}